// Round 7
// baseline (501.910 us; speedup 1.0000x reference)
//
#include <hip/hip_runtime.h>
#include <stdint.h>

typedef short short8 __attribute__((ext_vector_type(8)));
typedef float floatx4 __attribute__((ext_vector_type(4)));
typedef unsigned short ushort_t;

constexpr int cFH = 11, cFW = 20, cP = 2784, cPM1 = 2783, cD = 704;
constexpr int cAFC = 64, cBBC = 512, cNB = 8, cNPAD = 2816, cM = 22272;
constexpr int cFTR = 768;   // featT padded rows

static __device__ __forceinline__ unsigned short f2bf(float f) {
  union { float f; unsigned u; } v; v.f = f;
  unsigned r = v.u + 0x7fffu + ((v.u >> 16) & 1u);
  return (unsigned short)(r >> 16);
}
static __device__ __forceinline__ int imin(int a, int b) { return a < b ? a : b; }

// bijective XCD-chunk swizzle (m204)
static __device__ __forceinline__ int xcd_swz(int orig, int total) {
  int q = total >> 3, r = total & 7;
  int xcd = orig & 7, pos = orig >> 3;
  return (xcd < r ? xcd * (q + 1) : r * (q + 1) + (xcd - r) * q) + pos;
}

// async global->LDS, 16B per lane, wave-uniform LDS base + lane*16
static __device__ __forceinline__ void gload16(const ushort_t* g, ushort_t* l) {
  __builtin_amdgcn_global_load_lds(
      (const __attribute__((address_space(1))) unsigned int*)g,
      (__attribute__((address_space(3))) unsigned int*)l, 16, 0, 0);
}

#define BARX() asm volatile("s_barrier" ::: "memory")
#define VMW2() asm volatile("s_waitcnt vmcnt(2)" ::: "memory")

// ---- 8-phase template building blocks (names bound to kernel locals) ----
#define G8_LOADA(RH, KH) do { \
  _Pragma("unroll") for (int rf_ = 0; rf_ < 4; ++rf_) \
    afr[rf_] = *(const short8*)(LA + offA[RH][KH][rf_]); } while (0)

#define G8_LOADB(KH) do { \
  _Pragma("unroll") for (int cf_ = 0; cf_ < 4; ++cf_) \
    bfr[cf_] = *(const short8*)(LB + offB[KH][cf_]); } while (0)

#define G8_MFMA(RH) do { \
  __builtin_amdgcn_s_setprio(1); \
  _Pragma("unroll") for (int rf_ = 0; rf_ < 4; ++rf_) \
    _Pragma("unroll") for (int cf_ = 0; cf_ < 4; ++cf_) \
      acc[(RH)*4+rf_][cf_] = __builtin_amdgcn_mfma_f32_16x16x32_bf16( \
          afr[rf_], bfr[cf_], acc[(RH)*4+rf_][cf_], 0, 0, 0); \
  __builtin_amdgcn_s_setprio(0); } while (0)

#define G8_STAGE(PTR, MAT, CHUNK) do { \
  gload16(PTR, &lds[ns][MAT][(CHUNK)*4096 + wid*512]); PTR += 64; } while (0)

// offsets: LDS tile [256 rows][64 cols] bf16; block-col swizzle blk ^= (row>>1)&7
#define G8_SETUP_OFFSETS() \
  int offA[2][2][4], offB[2][4]; \
  { int key = ((lr >> 1) & 7) << 3; \
    _Pragma("unroll") for (int rh_ = 0; rh_ < 2; ++rh_) \
      _Pragma("unroll") for (int kh_ = 0; kh_ < 2; ++kh_) \
        _Pragma("unroll") for (int rf_ = 0; rf_ < 4; ++rf_) { \
          int arow = wm * 128 + rh_ * 64 + rf_ * 16 + lr; \
          offA[rh_][kh_][rf_] = arow * 64 + ((((kh_ * 4 + lg) << 3)) ^ key); } \
    _Pragma("unroll") for (int kh_ = 0; kh_ < 2; ++kh_) \
      _Pragma("unroll") for (int cf_ = 0; cf_ < 4; ++cf_) { \
        int brow = wn * 64 + cf_ * 16 + lr; \
        offB[kh_][cf_] = brow * 64 + ((((kh_ * 4 + lg) << 3)) ^ key); } }

#define G8_PROLOGUE() do { int ns = 0; \
  G8_STAGE(pB0,1,0); G8_STAGE(pB1,1,1); G8_STAGE(pB2,1,2); G8_STAGE(pB3,1,3); \
  G8_STAGE(pA0,0,0); G8_STAGE(pA2,0,2); G8_STAGE(pA1,0,1); G8_STAGE(pA3,0,3); \
  VMW2(); BARX(); } while (0)

#define G8_KLOOP(NT) \
  for (int t = 0; t < (NT); ++t) { \
    int s_ = t & 1, ns = s_ ^ 1; \
    const ushort_t* LA = &lds[s_][0][0]; \
    const ushort_t* LB = &lds[s_][1][0]; \
    bool st = (t + 1 < (NT)); \
    short8 afr[4], bfr[4]; \
    /* P1: (rh0, kh0) */ \
    G8_LOADB(0); G8_LOADA(0, 0); \
    if (st) { G8_STAGE(pB0,1,0); G8_STAGE(pB1,1,1); } \
    BARX(); G8_MFMA(0); VMW2(); BARX(); \
    /* P2: (rh1, kh0) */ \
    G8_LOADA(1, 0); \
    if (st) { G8_STAGE(pB2,1,2); G8_STAGE(pB3,1,3); } \
    BARX(); G8_MFMA(1); BARX(); \
    /* P3: (rh0, kh1) */ \
    G8_LOADB(1); G8_LOADA(0, 1); \
    if (st) { G8_STAGE(pA0,0,0); G8_STAGE(pA2,0,2); } \
    BARX(); G8_MFMA(0); BARX(); \
    /* P4: (rh1, kh1) */ \
    G8_LOADA(1, 1); \
    if (st) { G8_STAGE(pA1,0,1); G8_STAGE(pA3,0,3); } \
    BARX(); G8_MFMA(1); VMW2(); BARX(); \
  }

// ---------------- 1x1 conv, 4 output channels per thread
__global__ void k_conv4(const float* __restrict__ x, const float* __restrict__ w,
                        const float* __restrict__ bias, float* __restrict__ f) {
  int idx = blockIdx.x * 256 + threadIdx.x;
  if (idx >= cNB * 16 * 220) return;
  int yx = idx % 220;
  int og = (idx / 220) % 16;
  int b  = idx / (220 * 16);
  int o0 = og * 4;
  const float* xp = x + (size_t)b * cBBC * 220 + yx;
  const float* w0 = w + (size_t)o0 * cBBC;
  const float* w1 = w0 + cBBC;
  const float* w2 = w1 + cBBC;
  const float* w3 = w2 + cBBC;
  float a0 = 0.f, a1 = 0.f, a2 = 0.f, a3 = 0.f;
#pragma unroll 4
  for (int c = 0; c < cBBC; ++c) {
    float xv = xp[(size_t)c * 220];
    a0 += xv * w0[c]; a1 += xv * w1[c]; a2 += xv * w2[c]; a3 += xv * w3[c];
  }
  f[((size_t)(b * cAFC + o0) * 220) + yx]     = a0 + bias[o0];
  f[((size_t)(b * cAFC + o0 + 1) * 220) + yx] = a1 + bias[o0 + 1];
  f[((size_t)(b * cAFC + o0 + 2) * 220) + yx] = a2 + bias[o0 + 2];
  f[((size_t)(b * cAFC + o0 + 3) * 220) + yx] = a3 + bias[o0 + 3];
}

// ---------------- gather -> feat bf16 [22272][704]
__global__ void k_gather8(const float* __restrict__ f, const int* __restrict__ cut_x,
                          const unsigned char* __restrict__ invalid,
                          ushort_t* __restrict__ feat) {
  int idx = blockIdx.x * 256 + threadIdx.x;
  if (idx >= cM * 88) return;
  int d8  = (idx % 88) * 8;
  int row = idx / 88;
  int p = row % cP;
  int b = row / cP;
  short8 v;
#pragma unroll
  for (int e = 0; e < 8; ++e) {
    int d = d8 + e;
    int o = d / cFH, i = d - o * cFH;
    int cx = cut_x[p * cFH + i];
    float vv = invalid[p * cFH + i] ? 0.f : f[((size_t)(b * cAFC + o) * cFH + i) * cFW + cx];
    v[e] = (short)f2bf(vv);
  }
  *(short8*)&feat[(size_t)row * cD + d8] = v;
}

// ---------------- feat -> featT bf16 [bz][768][2816]
__global__ void k_transpose(const ushort_t* __restrict__ feat,
                            ushort_t* __restrict__ featT, int b_base) {
  __shared__ ushort_t tile[64][66];
  int bz = blockIdx.z;
  int b  = b_base + bz;
  int p0 = blockIdx.x * 64, d0 = blockIdx.y * 64;
  int t = threadIdx.x;
#pragma unroll
  for (int m = 0; m < 16; ++m) {
    int idx = t + m * 256; int r = idx >> 6, c = idx & 63;
    int p = p0 + r;
    tile[r][c] = (p < cP) ? feat[((size_t)b * cP + p) * cD + d0 + c] : (ushort_t)0;
  }
  __syncthreads();
#pragma unroll
  for (int m = 0; m < 16; ++m) {
    int idx = t + m * 256; int r = idx >> 6, c = idx & 63;
    featT[((size_t)bz * cFTR + d0 + r) * cNPAD + p0 + c] = tile[c][r];
  }
}

// ---------------- att_w -> bf16 padded [2816][704]  +  Wt [80][1408]
__global__ void k_prep_w(const float* __restrict__ att_w, const float* __restrict__ reg_w,
                         const float* __restrict__ cls_w,
                         ushort_t* __restrict__ attw, ushort_t* __restrict__ Wt) {
  int idx = blockIdx.x * 256 + threadIdx.x;
  constexpr int n1 = cNPAD * cD;
  if (idx < n1) {
    int r = idx / cD;
    attw[idx] = (r < cPM1) ? f2bf(att_w[idx]) : (ushort_t)0;
  } else {
    int j = idx - n1;
    if (j < 80 * 1408) {
      int r = j / 1408, k = j % 1408;
      float v = 0.f;
      if (r < 73) v = reg_w[(size_t)r * 1408 + k];
      else if (r < 75) v = cls_w[(size_t)(r - 73) * 1408 + k];
      Wt[j] = f2bf(v);
    }
  }
}

// ---------------- denom[i] = sum of 44 partial slots; zero Pp diagonal
__global__ void k_denom(const float* __restrict__ partial, float* __restrict__ denom,
                        ushort_t* __restrict__ Pp, int n, int p_base) {
  int i = blockIdx.x * 256 + threadIdx.x;
  if (i >= n) return;
  float s = 0.f;
#pragma unroll 4
  for (int q = 0; q < 44; ++q) s += partial[(size_t)q * cM + i];
  denom[i] = s;
  Pp[(size_t)i * cNPAD + ((p_base + i) % cP)] = 0;
}

// ---------------- GEMM 1 (256^2 8-phase): S = feat @ attw^T; exp; scatter; partials
__global__ __launch_bounds__(512, 2) void k_gemm_s8(
    const ushort_t* __restrict__ feat, const ushort_t* __restrict__ attw,
    const float* __restrict__ att_b, ushort_t* __restrict__ Pp,
    float* __restrict__ partial, int m_base, int m_count, int pp_base) {
  __shared__ __align__(16) ushort_t lds[2][2][16384];
  int wg = xcd_swz(blockIdx.x, gridDim.x);
  int ntile = wg % 11, mtile = wg / 11;   // n fastest: A-panel shared on-XCD
  int tid = threadIdx.x;
  int wid = tid >> 6, lane = tid & 63, lr = lane & 15, lg = lane >> 4;
  int wm = wid >> 2, wn = wid & 3;
  int m0 = m_base + mtile * 256;
  int n0 = ntile * 256;
  int rmax = m_base + m_count - 1;

  G8_SETUP_OFFSETS();

  int srow = tid >> 3;
  int gcol = (((tid & 7) ^ ((srow >> 1) & 7)) << 3);
  const ushort_t* pA0 = feat + (size_t)imin(m0 +   0 + srow, rmax) * cD + gcol;
  const ushort_t* pA1 = feat + (size_t)imin(m0 +  64 + srow, rmax) * cD + gcol;
  const ushort_t* pA2 = feat + (size_t)imin(m0 + 128 + srow, rmax) * cD + gcol;
  const ushort_t* pA3 = feat + (size_t)imin(m0 + 192 + srow, rmax) * cD + gcol;
  const ushort_t* pB0 = attw + (size_t)(n0 +   0 + srow) * cD + gcol;
  const ushort_t* pB1 = attw + (size_t)(n0 +  64 + srow) * cD + gcol;
  const ushort_t* pB2 = attw + (size_t)(n0 + 128 + srow) * cD + gcol;
  const ushort_t* pB3 = attw + (size_t)(n0 + 192 + srow) * cD + gcol;

  floatx4 acc[8][4];
  floatx4 zero = {0.f, 0.f, 0.f, 0.f};
#pragma unroll
  for (int a = 0; a < 8; ++a)
#pragma unroll
    for (int q = 0; q < 4; ++q) acc[a][q] = zero;

  G8_PROLOGUE();
  G8_KLOOP(11);   // K = 704 = 11 tiles of 64

  // epilogue: exp, scatter store (diag skip), per-row partial sums
  float ab[4]; int kc[4];
#pragma unroll
  for (int n = 0; n < 4; ++n) {
    int k = n0 + wn * 64 + n * 16 + lr;
    kc[n] = k;
    ab[n] = (k < cPM1) ? att_b[k] : 0.f;
  }
#pragma unroll
  for (int m = 0; m < 8; ++m) {
#pragma unroll
    for (int r = 0; r < 4; ++r) {
      int i = m0 + wm * 128 + m * 16 + lg * 4 + r;
      bool rowok = (unsigned)(i - m_base) < (unsigned)m_count;
      int il = i - pp_base;
      int pl = i % cP;
      float ssum = 0.f;
#pragma unroll
      for (int n = 0; n < 4; ++n) {
        int k = kc[n];
        if (k < cPM1) {
          float e = __expf(acc[m][n][r] + ab[n]);
          ssum += e;
          if (rowok) Pp[(size_t)il * cNPAD + k + (k >= pl ? 1 : 0)] = f2bf(e);
        } else if (k <= cNPAD - 2) {
          if (rowok) Pp[(size_t)il * cNPAD + k + 1] = 0;
        }
      }
      ssum += __shfl_xor(ssum, 1); ssum += __shfl_xor(ssum, 2);
      ssum += __shfl_xor(ssum, 4); ssum += __shfl_xor(ssum, 8);
      if (lr == 0 && rowok)
        partial[(size_t)(ntile * 4 + wn) * cM + il] = ssum;
    }
  }
}

// ---------------- GEMM 2 (256^2 8-phase): att_feat = (Pp @ featT^T) / denom
__global__ __launch_bounds__(512, 2) void k_gemm_pv8(
    const ushort_t* __restrict__ Pp, const ushort_t* __restrict__ featT,
    const float* __restrict__ denom, ushort_t* __restrict__ af,
    int b_base, int pp_base, int ft_base, int af_base) {
  __shared__ __align__(16) ushort_t lds[2][2][16384];
  int wg = xcd_swz(blockIdx.x, gridDim.x);
  int ntile = wg % 3;
  int mtile = (wg / 3) % 11;
  int b = b_base + wg / 33;
  int tid = threadIdx.x;
  int wid = tid >> 6, lane = tid & 63, lr = lane & 15, lg = lane >> 4;
  int wm = wid >> 2, wn = wid & 3;
  int m0l = mtile * 256;
  int n0 = ntile * 256;
  int bP = b * cP - pp_base;

  G8_SETUP_OFFSETS();

  int srow = tid >> 3;
  int gcol = (((tid & 7) ^ ((srow >> 1) & 7)) << 3);
  const ushort_t* fb = featT + (size_t)(b - ft_base) * cFTR * cNPAD;
  const ushort_t* pA0 = Pp + (size_t)(bP + imin(m0l +   0 + srow, cP - 1)) * cNPAD + gcol;
  const ushort_t* pA1 = Pp + (size_t)(bP + imin(m0l +  64 + srow, cP - 1)) * cNPAD + gcol;
  const ushort_t* pA2 = Pp + (size_t)(bP + imin(m0l + 128 + srow, cP - 1)) * cNPAD + gcol;
  const ushort_t* pA3 = Pp + (size_t)(bP + imin(m0l + 192 + srow, cP - 1)) * cNPAD + gcol;
  const ushort_t* pB0 = fb + (size_t)(n0 +   0 + srow) * cNPAD + gcol;
  const ushort_t* pB1 = fb + (size_t)(n0 +  64 + srow) * cNPAD + gcol;
  const ushort_t* pB2 = fb + (size_t)(n0 + 128 + srow) * cNPAD + gcol;
  const ushort_t* pB3 = fb + (size_t)(n0 + 192 + srow) * cNPAD + gcol;

  floatx4 acc[8][4];
  floatx4 zero = {0.f, 0.f, 0.f, 0.f};
#pragma unroll
  for (int a = 0; a < 8; ++a)
#pragma unroll
    for (int q = 0; q < 4; ++q) acc[a][q] = zero;

  G8_PROLOGUE();
  G8_KLOOP(44);   // K = 2816 = 44 tiles of 64

#pragma unroll
  for (int m = 0; m < 8; ++m) {
#pragma unroll
    for (int r = 0; r < 4; ++r) {
      int p = m0l + wm * 128 + m * 16 + lg * 4 + r;
      if (p >= cP) continue;
      float rdn = __builtin_amdgcn_rcpf(denom[bP + p]);
#pragma unroll
      for (int n = 0; n < 4; ++n) {
        int dd = n0 + wn * 64 + n * 16 + lr;
        if (dd < cD)
          af[((size_t)(b * cP + p) - af_base) * cD + dd] = f2bf(acc[m][n][r] * rdn);
      }
    }
  }
}

// ---------------- GEMM 3 (staged A): [att_feat|feat] @ Wt^T + epilogue
__global__ __launch_bounds__(256, 4) void k_gemm_out(
    const ushort_t* __restrict__ af, const ushort_t* __restrict__ feat,
    const ushort_t* __restrict__ Wt,
    const float* __restrict__ reg_b, const float* __restrict__ cls_b,
    const float* __restrict__ anchors,
    float* __restrict__ out0, float* __restrict__ out1,
    float* __restrict__ out2, float* __restrict__ out3,
    int m_base, int m_count, int af_base) {
  __shared__ __align__(16) ushort_t sA[2][128 * 32];
  int tid = threadIdx.x;
  int w = tid >> 6, l = tid & 63, lr = l & 15, lg = l >> 4;
  int wr = w * 32;
  int m0 = m_base + blockIdx.x * 128;
  int lastRow = m_base + m_count - 1;

  int srow = w * 16 + (l >> 2), scol = (l & 3) * 8;
  const ushort_t* pa0_af = af + (size_t)(imin(m0 + srow, lastRow) - af_base) * cD + scol;
  const ushort_t* pa1_af = af + (size_t)(imin(m0 + 64 + srow, lastRow) - af_base) * cD + scol;
  const ushort_t* pa0_f  = feat + (size_t)imin(m0 + srow, lastRow) * cD + scol;
  const ushort_t* pa1_f  = feat + (size_t)imin(m0 + 64 + srow, lastRow) * cD + scol;
  int lbase = w * 512;

  floatx4 zero = {0.f, 0.f, 0.f, 0.f};
  floatx4 acc[2][5];
#pragma unroll
  for (int a = 0; a < 2; ++a)
#pragma unroll
    for (int q = 0; q < 5; ++q) acc[a][q] = zero;

  auto stageA = [&](int buf, int kk) {
    const ushort_t *s0, *s1;
    if (kk < 22) { s0 = pa0_af + kk * 32; s1 = pa1_af + kk * 32; }
    else         { s0 = pa0_f + (kk - 22) * 32; s1 = pa1_f + (kk - 22) * 32; }
    gload16(s0, &sA[buf][lbase]);
    gload16(s1, &sA[buf][lbase + 2048]);
  };

  stageA(0, 0);
  __syncthreads();
  int cur = 0;
  for (int kk = 0; kk < 44; ++kk) {
    if (kk + 1 < 44) stageA(cur ^ 1, kk + 1);
    int kb = kk * 32 + lg * 8;
    short8 avv[2];
#pragma unroll
    for (int mt = 0; mt < 2; ++mt)
      avv[mt] = *(const short8*)&sA[cur][(wr + mt * 16 + lr) * 32 + lg * 8];
#pragma unroll
    for (int nt = 0; nt < 5; ++nt) {
      short8 bvv = *(const short8*)(Wt + (size_t)(nt * 16 + lr) * 1408 + kb);
#pragma unroll
      for (int mt = 0; mt < 2; ++mt)
        acc[mt][nt] = __builtin_amdgcn_mfma_f32_16x16x32_bf16(avv[mt], bvv, acc[mt][nt], 0, 0, 0);
    }
    __syncthreads();
    cur ^= 1;
  }

#pragma unroll
  for (int mt = 0; mt < 2; ++mt)
#pragma unroll
    for (int nt = 0; nt < 5; ++nt)
#pragma unroll
      for (int r = 0; r < 4; ++r) {
        int i = m0 + wr + mt * 16 + lg * 4 + r;
        if (i - m_base >= m_count) continue;
        int o = nt * 16 + lr;
        int p = i % cP;
        float v = acc[mt][nt][r];
        const float* an = anchors + (size_t)p * 74;
        if (o == 0)        { out2[i] = an[1] + v + reg_b[0]; out1[i] = an[0]; }
        else if (o < 73)   { out0[(size_t)i * 72 + (o - 1)] = an[1 + o] + v + reg_b[o]; }
        else if (o == 73)  { out3[(size_t)i * 2]     = v + cls_b[0]; }
        else if (o == 74)  { out3[(size_t)i * 2 + 1] = v + cls_b[1]; }
      }
}

extern "C" void kernel_launch(void* const* d_in, const int* in_sizes, int n_in,
                              void* d_out, int out_size, void* d_ws, size_t ws_size,
                              hipStream_t stream) {
  const float* x       = (const float*)d_in[0];
  const float* conv_w  = (const float*)d_in[1];
  const float* conv_b  = (const float*)d_in[2];
  const float* att_w   = (const float*)d_in[3];
  const float* att_b   = (const float*)d_in[4];
  const float* cls_w   = (const float*)d_in[5];
  const float* cls_b   = (const float*)d_in[6];
  const float* reg_w   = (const float*)d_in[7];
  const float* reg_b   = (const float*)d_in[8];
  const float* anchors = (const float*)d_in[9];
  const int*   cut_x   = (const int*)d_in[10];
  const unsigned char* invalid = (const unsigned char*)d_in[11];
  float* out0 = (float*)d_out;
  float* out1 = out0 + (size_t)cM * 72;
  float* out2 = out1 + cM;
  float* out3 = out2 + cM;

  size_t off = 0;
  char* base = (char*)d_ws;
  auto carve = [&](size_t bytes) -> void* {
    void* r = base + off; off += (bytes + 255) & ~(size_t)255; return r;
  };
  float* fbuf            = (float*)carve((size_t)cNB * cAFC * cFH * cFW * 4);
  ushort_t* feat         = (ushort_t*)carve((size_t)cM * cD * 2);
  ushort_t* attw         = (ushort_t*)carve((size_t)cNPAD * cD * 2);
  ushort_t* Wt           = (ushort_t*)carve((size_t)80 * 1408 * 2);
  float* partial         = (float*)carve((size_t)44 * cM * 4);
  float* denom           = (float*)carve((size_t)cM * 4);

  size_t featT_full = (size_t)cNB * cFTR * cNPAD * 2, featT_one = (size_t)cFTR * cNPAD * 2;
  size_t af_full    = (size_t)cM * cD * 2,            af_one    = (size_t)cP * cD * 2;
  size_t pp_full    = (size_t)cM * cNPAD * 2,         pp_one    = (size_t)cNPAD * cNPAD * 2;

  size_t needA = off + featT_full + af_full + pp_full;
  size_t needB = off + featT_full + af_full + pp_one;
  int mode = (ws_size >= needA) ? 0 : ((ws_size >= needB) ? 1 : 2);

  ushort_t *featT, *af, *Pp;
  if (mode == 0)      { featT = (ushort_t*)carve(featT_full); af = (ushort_t*)carve(af_full); Pp = (ushort_t*)carve(pp_full); }
  else if (mode == 1) { featT = (ushort_t*)carve(featT_full); af = (ushort_t*)carve(af_full); Pp = (ushort_t*)carve(pp_one); }
  else                { featT = (ushort_t*)carve(featT_one);  af = (ushort_t*)carve(af_one);  Pp = (ushort_t*)carve(pp_one); }

  k_conv4<<<(cNB * 16 * 220 + 255) / 256, 256, 0, stream>>>(x, conv_w, conv_b, fbuf);
  k_gather8<<<(cM * 88 + 255) / 256, 256, 0, stream>>>(fbuf, cut_x, invalid, feat);
  k_prep_w<<<(cNPAD * cD + 80 * 1408 + 255) / 256, 256, 0, stream>>>(att_w, reg_w, cls_w, attw, Wt);

  if (mode == 0) {
    k_transpose<<<dim3(44, 11, 8), 256, 0, stream>>>(feat, featT, 0);
    k_gemm_s8<<<87 * 11, 512, 0, stream>>>(feat, attw, att_b, Pp, partial, 0, cM, 0);
    k_denom<<<(cM + 255) / 256, 256, 0, stream>>>(partial, denom, Pp, cM, 0);
    k_gemm_pv8<<<8 * 11 * 3, 512, 0, stream>>>(Pp, featT, denom, af, 0, 0, 0, 0);
    k_gemm_out<<<174, 256, 0, stream>>>(af, feat, Wt, reg_b, cls_b, anchors,
                                        out0, out1, out2, out3, 0, cM, 0);
  } else if (mode == 1) {
    k_transpose<<<dim3(44, 11, 8), 256, 0, stream>>>(feat, featT, 0);
    for (int b = 0; b < cNB; ++b) {
      k_gemm_s8<<<11 * 11, 512, 0, stream>>>(feat, attw, att_b, Pp, partial, b * cP, cP, b * cP);
      k_denom<<<(cP + 255) / 256, 256, 0, stream>>>(partial, denom, Pp, cP, b * cP);
      k_gemm_pv8<<<11 * 3, 512, 0, stream>>>(Pp, featT, denom, af, b, b * cP, 0, 0);
    }
    k_gemm_out<<<174, 256, 0, stream>>>(af, feat, Wt, reg_b, cls_b, anchors,
                                        out0, out1, out2, out3, 0, cM, 0);
  } else {
    for (int b = 0; b < cNB; ++b) {
      k_transpose<<<dim3(44, 11, 1), 256, 0, stream>>>(feat, featT, b);
      k_gemm_s8<<<11 * 11, 512, 0, stream>>>(feat, attw, att_b, Pp, partial, b * cP, cP, b * cP);
      k_denom<<<(cP + 255) / 256, 256, 0, stream>>>(partial, denom, Pp, cP, b * cP);
      k_gemm_pv8<<<11 * 3, 512, 0, stream>>>(Pp, featT, denom, af, b, b * cP, b, b * cP);
      k_gemm_out<<<22, 256, 0, stream>>>(af, feat, Wt, reg_b, cls_b, anchors,
                                         out0, out1, out2, out3, b * cP, cP, b * cP);
    }
  }
}

// Round 8
// 494.842 us; speedup vs baseline: 1.0143x; 1.0143x over previous
//
#include <hip/hip_runtime.h>
#include <stdint.h>

typedef short short8 __attribute__((ext_vector_type(8)));
typedef float floatx4 __attribute__((ext_vector_type(4)));
typedef unsigned short ushort_t;

constexpr int cFH = 11, cFW = 20, cP = 2784, cPM1 = 2783, cD = 704;
constexpr int cAFC = 64, cBBC = 512, cNB = 8, cNPAD = 2816, cM = 22272;
constexpr int cFTR = 768;   // featT padded rows

static __device__ __forceinline__ unsigned short f2bf(float f) {
  union { float f; unsigned u; } v; v.f = f;
  unsigned r = v.u + 0x7fffu + ((v.u >> 16) & 1u);
  return (unsigned short)(r >> 16);
}
static __device__ __forceinline__ int imin(int a, int b) { return a < b ? a : b; }

// bijective XCD-chunk swizzle (m204)
static __device__ __forceinline__ int xcd_swz(int orig, int total) {
  int q = total >> 3, r = total & 7;
  int xcd = orig & 7, pos = orig >> 3;
  return (xcd < r ? xcd * (q + 1) : r * (q + 1) + (xcd - r) * q) + pos;
}

// async global->LDS, 16B per lane, wave-uniform LDS base + lane*16
static __device__ __forceinline__ void gload16(const ushort_t* g, ushort_t* l) {
  __builtin_amdgcn_global_load_lds(
      (const __attribute__((address_space(1))) unsigned int*)g,
      (__attribute__((address_space(3))) unsigned int*)l, 16, 0, 0);
}

#define BARX() asm volatile("s_barrier" ::: "memory")
#define VMW2() asm volatile("s_waitcnt vmcnt(2)" ::: "memory")

// ---- 8-phase template building blocks (names bound to kernel locals) ----
#define G8_LOADA(RH, KH) do { \
  _Pragma("unroll") for (int rf_ = 0; rf_ < 4; ++rf_) \
    afr[rf_] = *(const short8*)(LA + offA[RH][KH][rf_]); } while (0)

#define G8_LOADB(KH) do { \
  _Pragma("unroll") for (int cf_ = 0; cf_ < 4; ++cf_) \
    bfr[cf_] = *(const short8*)(LB + offB[KH][cf_]); } while (0)

#define G8_MFMA(RH) do { \
  __builtin_amdgcn_s_setprio(1); \
  _Pragma("unroll") for (int rf_ = 0; rf_ < 4; ++rf_) \
    _Pragma("unroll") for (int cf_ = 0; cf_ < 4; ++cf_) \
      acc[(RH)*4+rf_][cf_] = __builtin_amdgcn_mfma_f32_16x16x32_bf16( \
          afr[rf_], bfr[cf_], acc[(RH)*4+rf_][cf_], 0, 0, 0); \
  __builtin_amdgcn_s_setprio(0); } while (0)

#define G8_STAGE(PTR, MAT, CHUNK) do { \
  gload16(PTR, &lds[ns][MAT][(CHUNK)*4096 + wid*512]); PTR += 64; } while (0)

// offsets: LDS tile [256 rows][64 cols] bf16; block-col swizzle blk ^= (row>>1)&7
#define G8_SETUP_OFFSETS() \
  int offA[2][2][4], offB[2][4]; \
  { int key = ((lr >> 1) & 7) << 3; \
    _Pragma("unroll") for (int rh_ = 0; rh_ < 2; ++rh_) \
      _Pragma("unroll") for (int kh_ = 0; kh_ < 2; ++kh_) \
        _Pragma("unroll") for (int rf_ = 0; rf_ < 4; ++rf_) { \
          int arow = wm * 128 + rh_ * 64 + rf_ * 16 + lr; \
          offA[rh_][kh_][rf_] = arow * 64 + ((((kh_ * 4 + lg) << 3)) ^ key); } \
    _Pragma("unroll") for (int kh_ = 0; kh_ < 2; ++kh_) \
      _Pragma("unroll") for (int cf_ = 0; cf_ < 4; ++cf_) { \
        int brow = wn * 64 + cf_ * 16 + lr; \
        offB[kh_][cf_] = brow * 64 + ((((kh_ * 4 + lg) << 3)) ^ key); } }

#define G8_PROLOGUE() do { int ns = 0; \
  G8_STAGE(pB0,1,0); G8_STAGE(pB1,1,1); G8_STAGE(pB2,1,2); G8_STAGE(pB3,1,3); \
  G8_STAGE(pA0,0,0); G8_STAGE(pA2,0,2); G8_STAGE(pA1,0,1); G8_STAGE(pA3,0,3); \
  VMW2(); BARX(); } while (0)

#define G8_KLOOP(NT) \
  for (int t = 0; t < (NT); ++t) { \
    int s_ = t & 1, ns = s_ ^ 1; \
    const ushort_t* LA = &lds[s_][0][0]; \
    const ushort_t* LB = &lds[s_][1][0]; \
    bool st = (t + 1 < (NT)); \
    short8 afr[4], bfr[4]; \
    /* P1: (rh0, kh0) */ \
    G8_LOADB(0); G8_LOADA(0, 0); \
    if (st) { G8_STAGE(pB0,1,0); G8_STAGE(pB1,1,1); } \
    BARX(); G8_MFMA(0); VMW2(); BARX(); \
    /* P2: (rh1, kh0) */ \
    G8_LOADA(1, 0); \
    if (st) { G8_STAGE(pB2,1,2); G8_STAGE(pB3,1,3); } \
    BARX(); G8_MFMA(1); BARX(); \
    /* P3: (rh0, kh1) */ \
    G8_LOADB(1); G8_LOADA(0, 1); \
    if (st) { G8_STAGE(pA0,0,0); G8_STAGE(pA2,0,2); } \
    BARX(); G8_MFMA(0); BARX(); \
    /* P4: (rh1, kh1) */ \
    G8_LOADA(1, 1); \
    if (st) { G8_STAGE(pA1,0,1); G8_STAGE(pA3,0,3); } \
    BARX(); G8_MFMA(1); VMW2(); BARX(); \
  }

// ---------------- 1x1 conv, 4 output channels per thread
__global__ void k_conv4(const float* __restrict__ x, const float* __restrict__ w,
                        const float* __restrict__ bias, float* __restrict__ f) {
  int idx = blockIdx.x * 256 + threadIdx.x;
  if (idx >= cNB * 16 * 220) return;
  int yx = idx % 220;
  int og = (idx / 220) % 16;
  int b  = idx / (220 * 16);
  int o0 = og * 4;
  const float* xp = x + (size_t)b * cBBC * 220 + yx;
  const float* w0 = w + (size_t)o0 * cBBC;
  const float* w1 = w0 + cBBC;
  const float* w2 = w1 + cBBC;
  const float* w3 = w2 + cBBC;
  float a0 = 0.f, a1 = 0.f, a2 = 0.f, a3 = 0.f;
#pragma unroll 4
  for (int c = 0; c < cBBC; ++c) {
    float xv = xp[(size_t)c * 220];
    a0 += xv * w0[c]; a1 += xv * w1[c]; a2 += xv * w2[c]; a3 += xv * w3[c];
  }
  f[((size_t)(b * cAFC + o0) * 220) + yx]     = a0 + bias[o0];
  f[((size_t)(b * cAFC + o0 + 1) * 220) + yx] = a1 + bias[o0 + 1];
  f[((size_t)(b * cAFC + o0 + 2) * 220) + yx] = a2 + bias[o0 + 2];
  f[((size_t)(b * cAFC + o0 + 3) * 220) + yx] = a3 + bias[o0 + 3];
}

// ---------------- gather -> feat bf16 [22272][704]
__global__ void k_gather8(const float* __restrict__ f, const int* __restrict__ cut_x,
                          const unsigned char* __restrict__ invalid,
                          ushort_t* __restrict__ feat) {
  int idx = blockIdx.x * 256 + threadIdx.x;
  if (idx >= cM * 88) return;
  int d8  = (idx % 88) * 8;
  int row = idx / 88;
  int p = row % cP;
  int b = row / cP;
  short8 v;
#pragma unroll
  for (int e = 0; e < 8; ++e) {
    int d = d8 + e;
    int o = d / cFH, i = d - o * cFH;
    int cx = cut_x[p * cFH + i];
    float vv = invalid[p * cFH + i] ? 0.f : f[((size_t)(b * cAFC + o) * cFH + i) * cFW + cx];
    v[e] = (short)f2bf(vv);
  }
  *(short8*)&feat[(size_t)row * cD + d8] = v;
}

// ---------------- feat -> featT bf16 [bz][768][2816]
__global__ void k_transpose(const ushort_t* __restrict__ feat,
                            ushort_t* __restrict__ featT, int b_base) {
  __shared__ ushort_t tile[64][66];
  int bz = blockIdx.z;
  int b  = b_base + bz;
  int p0 = blockIdx.x * 64, d0 = blockIdx.y * 64;
  int t = threadIdx.x;
#pragma unroll
  for (int m = 0; m < 16; ++m) {
    int idx = t + m * 256; int r = idx >> 6, c = idx & 63;
    int p = p0 + r;
    tile[r][c] = (p < cP) ? feat[((size_t)b * cP + p) * cD + d0 + c] : (ushort_t)0;
  }
  __syncthreads();
#pragma unroll
  for (int m = 0; m < 16; ++m) {
    int idx = t + m * 256; int r = idx >> 6, c = idx & 63;
    featT[((size_t)bz * cFTR + d0 + r) * cNPAD + p0 + c] = tile[c][r];
  }
}

// ---------------- att_w -> bf16 padded [2816][704]  +  Wt [80][1408]
__global__ void k_prep_w(const float* __restrict__ att_w, const float* __restrict__ reg_w,
                         const float* __restrict__ cls_w,
                         ushort_t* __restrict__ attw, ushort_t* __restrict__ Wt) {
  int idx = blockIdx.x * 256 + threadIdx.x;
  constexpr int n1 = cNPAD * cD;
  if (idx < n1) {
    int r = idx / cD;
    attw[idx] = (r < cPM1) ? f2bf(att_w[idx]) : (ushort_t)0;
  } else {
    int j = idx - n1;
    if (j < 80 * 1408) {
      int r = j / 1408, k = j % 1408;
      float v = 0.f;
      if (r < 73) v = reg_w[(size_t)r * 1408 + k];
      else if (r < 75) v = cls_w[(size_t)(r - 73) * 1408 + k];
      Wt[j] = f2bf(v);
    }
  }
}

// ---------------- denom[i] = sum of 44 partial slots; zero Pp diagonal
__global__ void k_denom(const float* __restrict__ partial, float* __restrict__ denom,
                        ushort_t* __restrict__ Pp, int n, int p_base) {
  int i = blockIdx.x * 256 + threadIdx.x;
  if (i >= n) return;
  float s = 0.f;
#pragma unroll 4
  for (int q = 0; q < 44; ++q) s += partial[(size_t)q * cM + i];
  denom[i] = s;
  Pp[(size_t)i * cNPAD + ((p_base + i) % cP)] = 0;
}

// ---------------- GEMM 1 (256^2 8-phase): S = feat @ attw^T; exp; scatter; partials
__global__ __launch_bounds__(512, 2) void k_gemm_s8(
    const ushort_t* __restrict__ feat, const ushort_t* __restrict__ attw,
    const float* __restrict__ att_b, ushort_t* __restrict__ Pp,
    float* __restrict__ partial, int m_base, int m_count, int pp_base) {
  __shared__ __align__(16) ushort_t lds[2][2][16384];
  int wg = xcd_swz(blockIdx.x, gridDim.x);
  int ntile = wg % 11, mtile = wg / 11;   // n fastest: A-panel shared on-XCD
  int tid = threadIdx.x;
  int wid = tid >> 6, lane = tid & 63, lr = lane & 15, lg = lane >> 4;
  int wm = wid >> 2, wn = wid & 3;
  int m0 = m_base + mtile * 256;
  int n0 = ntile * 256;
  int rmax = m_base + m_count - 1;

  G8_SETUP_OFFSETS();

  int srow = tid >> 3;
  int gcol = (((tid & 7) ^ ((srow >> 1) & 7)) << 3);
  const ushort_t* pA0 = feat + (size_t)imin(m0 +   0 + srow, rmax) * cD + gcol;
  const ushort_t* pA1 = feat + (size_t)imin(m0 +  64 + srow, rmax) * cD + gcol;
  const ushort_t* pA2 = feat + (size_t)imin(m0 + 128 + srow, rmax) * cD + gcol;
  const ushort_t* pA3 = feat + (size_t)imin(m0 + 192 + srow, rmax) * cD + gcol;
  const ushort_t* pB0 = attw + (size_t)(n0 +   0 + srow) * cD + gcol;
  const ushort_t* pB1 = attw + (size_t)(n0 +  64 + srow) * cD + gcol;
  const ushort_t* pB2 = attw + (size_t)(n0 + 128 + srow) * cD + gcol;
  const ushort_t* pB3 = attw + (size_t)(n0 + 192 + srow) * cD + gcol;

  floatx4 acc[8][4];
  floatx4 zero = {0.f, 0.f, 0.f, 0.f};
#pragma unroll
  for (int a = 0; a < 8; ++a)
#pragma unroll
    for (int q = 0; q < 4; ++q) acc[a][q] = zero;

  G8_PROLOGUE();
  G8_KLOOP(11);   // K = 704 = 11 tiles of 64

  // epilogue: exp, scatter store (diag skip), per-row partial sums
  float ab[4]; int kc[4];
#pragma unroll
  for (int n = 0; n < 4; ++n) {
    int k = n0 + wn * 64 + n * 16 + lr;
    kc[n] = k;
    ab[n] = (k < cPM1) ? att_b[k] : 0.f;
  }
#pragma unroll
  for (int m = 0; m < 8; ++m) {
#pragma unroll
    for (int r = 0; r < 4; ++r) {
      int i = m0 + wm * 128 + m * 16 + lg * 4 + r;
      bool rowok = (unsigned)(i - m_base) < (unsigned)m_count;
      int il = i - pp_base;
      int pl = i % cP;
      float ssum = 0.f;
#pragma unroll
      for (int n = 0; n < 4; ++n) {
        int k = kc[n];
        if (k < cPM1) {
          float e = __expf(acc[m][n][r] + ab[n]);
          ssum += e;
          if (rowok) Pp[(size_t)il * cNPAD + k + (k >= pl ? 1 : 0)] = f2bf(e);
        } else if (k <= cNPAD - 2) {
          if (rowok) Pp[(size_t)il * cNPAD + k + 1] = 0;
        }
      }
      ssum += __shfl_xor(ssum, 1); ssum += __shfl_xor(ssum, 2);
      ssum += __shfl_xor(ssum, 4); ssum += __shfl_xor(ssum, 8);
      if (lr == 0 && rowok)
        partial[(size_t)(ntile * 4 + wn) * cM + il] = ssum;
    }
  }
}

// ---------------- GEMM 2 (256^2 8-phase): att_feat = (Pp @ featT^T) / denom
__global__ __launch_bounds__(512, 2) void k_gemm_pv8(
    const ushort_t* __restrict__ Pp, const ushort_t* __restrict__ featT,
    const float* __restrict__ denom, ushort_t* __restrict__ af,
    int b_base, int pp_base, int ft_base, int af_base) {
  __shared__ __align__(16) ushort_t lds[2][2][16384];
  int wg = xcd_swz(blockIdx.x, gridDim.x);
  int ntile = wg % 3;
  int mtile = (wg / 3) % 11;
  int b = b_base + wg / 33;
  int tid = threadIdx.x;
  int wid = tid >> 6, lane = tid & 63, lr = lane & 15, lg = lane >> 4;
  int wm = wid >> 2, wn = wid & 3;
  int m0l = mtile * 256;
  int n0 = ntile * 256;
  int bP = b * cP - pp_base;

  G8_SETUP_OFFSETS();

  int srow = tid >> 3;
  int gcol = (((tid & 7) ^ ((srow >> 1) & 7)) << 3);
  const ushort_t* fb = featT + (size_t)(b - ft_base) * cFTR * cNPAD;
  const ushort_t* pA0 = Pp + (size_t)(bP + imin(m0l +   0 + srow, cP - 1)) * cNPAD + gcol;
  const ushort_t* pA1 = Pp + (size_t)(bP + imin(m0l +  64 + srow, cP - 1)) * cNPAD + gcol;
  const ushort_t* pA2 = Pp + (size_t)(bP + imin(m0l + 128 + srow, cP - 1)) * cNPAD + gcol;
  const ushort_t* pA3 = Pp + (size_t)(bP + imin(m0l + 192 + srow, cP - 1)) * cNPAD + gcol;
  const ushort_t* pB0 = fb + (size_t)(n0 +   0 + srow) * cNPAD + gcol;
  const ushort_t* pB1 = fb + (size_t)(n0 +  64 + srow) * cNPAD + gcol;
  const ushort_t* pB2 = fb + (size_t)(n0 + 128 + srow) * cNPAD + gcol;
  const ushort_t* pB3 = fb + (size_t)(n0 + 192 + srow) * cNPAD + gcol;

  floatx4 acc[8][4];
  floatx4 zero = {0.f, 0.f, 0.f, 0.f};
#pragma unroll
  for (int a = 0; a < 8; ++a)
#pragma unroll
    for (int q = 0; q < 4; ++q) acc[a][q] = zero;

  G8_PROLOGUE();
  G8_KLOOP(44);   // K = 2816 = 44 tiles of 64

#pragma unroll
  for (int m = 0; m < 8; ++m) {
#pragma unroll
    for (int r = 0; r < 4; ++r) {
      int p = m0l + wm * 128 + m * 16 + lg * 4 + r;
      if (p >= cP) continue;
      float rdn = __builtin_amdgcn_rcpf(denom[bP + p]);
#pragma unroll
      for (int n = 0; n < 4; ++n) {
        int dd = n0 + wn * 64 + n * 16 + lr;
        if (dd < cD)
          af[((size_t)(b * cP + p) - af_base) * cD + dd] = f2bf(acc[m][n][r] * rdn);
      }
    }
  }
}

// ---------------- GEMM 3 (staged A): [att_feat|feat] @ Wt^T + epilogue
__global__ __launch_bounds__(256, 4) void k_gemm_out(
    const ushort_t* __restrict__ af, const ushort_t* __restrict__ feat,
    const ushort_t* __restrict__ Wt,
    const float* __restrict__ reg_b, const float* __restrict__ cls_b,
    const float* __restrict__ anchors,
    float* __restrict__ out0, float* __restrict__ out1,
    float* __restrict__ out2, float* __restrict__ out3,
    int m_base, int m_count, int af_base) {
  __shared__ __align__(16) ushort_t sA[2][128 * 32];
  int tid = threadIdx.x;
  int w = tid >> 6, l = tid & 63, lr = l & 15, lg = l >> 4;
  int wr = w * 32;
  int m0 = m_base + blockIdx.x * 128;
  int lastRow = m_base + m_count - 1;

  int srow = w * 16 + (l >> 2), scol = (l & 3) * 8;
  const ushort_t* pa0_af = af + (size_t)(imin(m0 + srow, lastRow) - af_base) * cD + scol;
  const ushort_t* pa1_af = af + (size_t)(imin(m0 + 64 + srow, lastRow) - af_base) * cD + scol;
  const ushort_t* pa0_f  = feat + (size_t)imin(m0 + srow, lastRow) * cD + scol;
  const ushort_t* pa1_f  = feat + (size_t)imin(m0 + 64 + srow, lastRow) * cD + scol;
  int lbase = w * 512;

  floatx4 zero = {0.f, 0.f, 0.f, 0.f};
  floatx4 acc[2][5];
#pragma unroll
  for (int a = 0; a < 2; ++a)
#pragma unroll
    for (int q = 0; q < 5; ++q) acc[a][q] = zero;

  auto stageA = [&](int buf, int kk) {
    const ushort_t *s0, *s1;
    if (kk < 22) { s0 = pa0_af + kk * 32; s1 = pa1_af + kk * 32; }
    else         { s0 = pa0_f + (kk - 22) * 32; s1 = pa1_f + (kk - 22) * 32; }
    gload16(s0, &sA[buf][lbase]);
    gload16(s1, &sA[buf][lbase + 2048]);
  };

  stageA(0, 0);
  __syncthreads();
  int cur = 0;
  for (int kk = 0; kk < 44; ++kk) {
    if (kk + 1 < 44) stageA(cur ^ 1, kk + 1);
    int kb = kk * 32 + lg * 8;
    short8 avv[2];
#pragma unroll
    for (int mt = 0; mt < 2; ++mt)
      avv[mt] = *(const short8*)&sA[cur][(wr + mt * 16 + lr) * 32 + lg * 8];
#pragma unroll
    for (int nt = 0; nt < 5; ++nt) {
      short8 bvv = *(const short8*)(Wt + (size_t)(nt * 16 + lr) * 1408 + kb);
#pragma unroll
      for (int mt = 0; mt < 2; ++mt)
        acc[mt][nt] = __builtin_amdgcn_mfma_f32_16x16x32_bf16(avv[mt], bvv, acc[mt][nt], 0, 0, 0);
    }
    __syncthreads();
    cur ^= 1;
  }

#pragma unroll
  for (int mt = 0; mt < 2; ++mt)
#pragma unroll
    for (int nt = 0; nt < 5; ++nt)
#pragma unroll
      for (int r = 0; r < 4; ++r) {
        int i = m0 + wr + mt * 16 + lg * 4 + r;
        if (i - m_base >= m_count) continue;
        int o = nt * 16 + lr;
        int p = i % cP;
        float v = acc[mt][nt][r];
        const float* an = anchors + (size_t)p * 74;
        if (o == 0)        { out2[i] = an[1] + v + reg_b[0]; out1[i] = an[0]; }
        else if (o < 73)   { out0[(size_t)i * 72 + (o - 1)] = an[1 + o] + v + reg_b[o]; }
        else if (o == 73)  { out3[(size_t)i * 2]     = v + cls_b[0]; }
        else if (o == 74)  { out3[(size_t)i * 2 + 1] = v + cls_b[1]; }
      }
}

extern "C" void kernel_launch(void* const* d_in, const int* in_sizes, int n_in,
                              void* d_out, int out_size, void* d_ws, size_t ws_size,
                              hipStream_t stream) {
  const float* x       = (const float*)d_in[0];
  const float* conv_w  = (const float*)d_in[1];
  const float* conv_b  = (const float*)d_in[2];
  const float* att_w   = (const float*)d_in[3];
  const float* att_b   = (const float*)d_in[4];
  const float* cls_w   = (const float*)d_in[5];
  const float* cls_b   = (const float*)d_in[6];
  const float* reg_w   = (const float*)d_in[7];
  const float* reg_b   = (const float*)d_in[8];
  const float* anchors = (const float*)d_in[9];
  const int*   cut_x   = (const int*)d_in[10];
  const unsigned char* invalid = (const unsigned char*)d_in[11];
  float* out0 = (float*)d_out;
  float* out1 = out0 + (size_t)cM * 72;
  float* out2 = out1 + cM;
  float* out3 = out2 + cM;

  size_t off = 0;
  char* base = (char*)d_ws;
  auto carve = [&](size_t bytes) -> void* {
    void* r = base + off; off += (bytes + 255) & ~(size_t)255; return r;
  };
  float* fbuf            = (float*)carve((size_t)cNB * cAFC * cFH * cFW * 4);
  ushort_t* feat         = (ushort_t*)carve((size_t)cM * cD * 2);
  ushort_t* attw         = (ushort_t*)carve((size_t)cNPAD * cD * 2);
  ushort_t* Wt           = (ushort_t*)carve((size_t)80 * 1408 * 2);
  float* partial         = (float*)carve((size_t)44 * cM * 4);
  float* denom           = (float*)carve((size_t)cM * 4);

  size_t featT_full = (size_t)cNB * cFTR * cNPAD * 2, featT_one = (size_t)cFTR * cNPAD * 2;
  size_t af_full    = (size_t)cM * cD * 2,            af_one    = (size_t)cP * cD * 2;
  size_t pp_full    = (size_t)cM * cNPAD * 2,         pp_one    = (size_t)cNPAD * cNPAD * 2;

  size_t needA = off + featT_full + af_full + pp_full;
  size_t needB = off + featT_full + af_full + pp_one;
  int mode = (ws_size >= needA) ? 0 : ((ws_size >= needB) ? 1 : 2);

  ushort_t *featT, *af, *Pp;
  if (mode == 0)      { featT = (ushort_t*)carve(featT_full); af = (ushort_t*)carve(af_full); Pp = (ushort_t*)carve(pp_full); }
  else if (mode == 1) { featT = (ushort_t*)carve(featT_full); af = (ushort_t*)carve(af_full); Pp = (ushort_t*)carve(pp_one); }
  else                { featT = (ushort_t*)carve(featT_one);  af = (ushort_t*)carve(af_one);  Pp = (ushort_t*)carve(pp_one); }

  k_conv4<<<(cNB * 16 * 220 + 255) / 256, 256, 0, stream>>>(x, conv_w, conv_b, fbuf);
  k_gather8<<<(cM * 88 + 255) / 256, 256, 0, stream>>>(fbuf, cut_x, invalid, feat);
  k_prep_w<<<(cNPAD * cD + 80 * 1408 + 255) / 256, 256, 0, stream>>>(att_w, reg_w, cls_w, attw, Wt);

  if (mode == 0) {
    k_transpose<<<dim3(44, 11, 8), 256, 0, stream>>>(feat, featT, 0);
    k_gemm_s8<<<87 * 11, 512, 0, stream>>>(feat, attw, att_b, Pp, partial, 0, cM, 0);
    k_denom<<<(cM + 255) / 256, 256, 0, stream>>>(partial, denom, Pp, cM, 0);
    k_gemm_pv8<<<8 * 11 * 3, 512, 0, stream>>>(Pp, featT, denom, af, 0, 0, 0, 0);
    k_gemm_out<<<174, 256, 0, stream>>>(af, feat, Wt, reg_b, cls_b, anchors,
                                        out0, out1, out2, out3, 0, cM, 0);
  } else if (mode == 1) {
    k_transpose<<<dim3(44, 11, 8), 256, 0, stream>>>(feat, featT, 0);
    for (int b = 0; b < cNB; ++b) {
      k_gemm_s8<<<11 * 11, 512, 0, stream>>>(feat, attw, att_b, Pp, partial, b * cP, cP, b * cP);
      k_denom<<<(cP + 255) / 256, 256, 0, stream>>>(partial, denom, Pp, cP, b * cP);
      k_gemm_pv8<<<11 * 3, 512, 0, stream>>>(Pp, featT, denom, af, b, b * cP, 0, 0);
    }
    k_gemm_out<<<174, 256, 0, stream>>>(af, feat, Wt, reg_b, cls_b, anchors,
                                        out0, out1, out2, out3, 0, cM, 0);
  } else {
    for (int b = 0; b < cNB; ++b) {
      k_transpose<<<dim3(44, 11, 1), 256, 0, stream>>>(feat, featT, b);
      k_gemm_s8<<<11 * 11, 512, 0, stream>>>(feat, attw, att_b, Pp, partial, b * cP, cP, b * cP);
      k_denom<<<(cP + 255) / 256, 256, 0, stream>>>(partial, denom, Pp, cP, b * cP);
      k_gemm_pv8<<<11 * 3, 512, 0, stream>>>(Pp, featT, denom, af, b, b * cP, b, b * cP);
      k_gemm_out<<<22, 256, 0, stream>>>(af, feat, Wt, reg_b, cls_b, anchors,
                                         out0, out1, out2, out3, b * cP, cP, b * cP);
    }
  }
}